// Round 15
// baseline (37.724 us; speedup 1.0000x reference)
//
#include <hip/hip_runtime.h>

#define CDIM 128
#define HDIM 128
#define LIM  40960   // nodes cached in edge LDS (x4 B = 163840 B = full 160 KiB)

typedef short bf16x8 __attribute__((ext_vector_type(8)));
typedef float f32x16 __attribute__((ext_vector_type(16)));

// fp32 -> bf16 bits, round-to-nearest-even
static __device__ __forceinline__ short f2bf(float f) {
    union { float f; unsigned u; } v; v.f = f;
    unsigned r = v.u + 0x7FFFu + ((v.u >> 16) & 1u);
    return (short)(r >> 16);
}
static __device__ __forceinline__ unsigned pack2(float a, float b) {
    return (unsigned)(unsigned short)f2bf(a) | ((unsigned)(unsigned short)f2bf(b) << 16);
}

// ---------------------------------------------------------------------------
// K1: node MLP -> bf16x2 score table. R8 logic with ONE-layer LDS (34.5 KB)
// -> 4 blocks/CU (16 waves/CU, 2x R8 occupancy). W2 transform mid-kernel.
// ---------------------------------------------------------------------------
__global__ __launch_bounds__(256, 4) void node_mfma(
    const float* __restrict__ x,
    const float* __restrict__ W1, const float* __restrict__ b1,
    const float* __restrict__ W2, const float* __restrict__ b2,
    const float* __restrict__ We,
    unsigned* __restrict__ tab, int N)
{
    __shared__ __align__(16) short wf[16384];   // 32 KB: ONE layer
    __shared__ __align__(16) float cv[512];     // b1 | b2 | Wq | Wk

    const int tid = threadIdx.x;
    const int l   = tid & 63;
    const int col = l & 31;
    const int hi  = l >> 5;
    const int node = blockIdx.x * 128 + (tid >> 6) * 32 + col;

    // ---- issue ALL x loads first (latency hides under W1 transform) ----
    const int nclamp = (node < N) ? node : (N - 1);
    const float* xb = &x[(size_t)nclamp * CDIM + hi * 8];
    float4 xr[16];
#pragma unroll
    for (int ks = 0; ks < 8; ks++) {
        xr[2 * ks]     = *(const float4*)(xb + ks * 16);
        xr[2 * ks + 1] = *(const float4*)(xb + ks * 16 + 4);
    }

    // ---- W1 transform: dest-linear, 1 ds_write_b128/iter ----
#pragma unroll
    for (int t = 0; t < 8; t++) {
        int rem = t * 256 + tid;                 // 0..2047
        int lv = rem & 63, ks = (rem >> 6) & 7, ct = rem >> 9;
        int k0 = ks * 16 + 8 * (lv >> 5);
        int n  = ct * 32 + (lv & 31);
        bf16x8 wv;
#pragma unroll
        for (int j = 0; j < 8; j++) wv[j] = f2bf(W1[(k0 + j) * HDIM + n]);
        *(bf16x8*)&wf[rem * 8] = wv;
    }
    for (int i = tid; i < 512; i += 256)
        cv[i] = (i < 128) ? b1[i] : (i < 256) ? b2[i - 128] : We[i - 256];

    // ---- convert x to bf16 fragments ----
    bf16x8 af[8];
#pragma unroll
    for (int ks = 0; ks < 8; ks++) {
        float4 v0 = xr[2 * ks], v1 = xr[2 * ks + 1];
        af[ks][0] = f2bf(v0.x); af[ks][1] = f2bf(v0.y);
        af[ks][2] = f2bf(v0.z); af[ks][3] = f2bf(v0.w);
        af[ks][4] = f2bf(v1.x); af[ks][5] = f2bf(v1.y);
        af[ks][6] = f2bf(v1.z); af[ks][7] = f2bf(v1.w);
    }
    __syncthreads();   // wf(W1) + cv ready

    const f32x16 zz = {0.f,0.f,0.f,0.f,0.f,0.f,0.f,0.f,0.f,0.f,0.f,0.f,0.f,0.f,0.f,0.f};

    // ---- layer 1: A = W1-frag (LDS, lane-linear), B = x^T-frag (regs) ----
    f32x16 acc[4];
#pragma unroll
    for (int ct = 0; ct < 4; ct++) acc[ct] = zz;
#pragma unroll
    for (int ks = 0; ks < 8; ks++) {
#pragma unroll
        for (int ct = 0; ct < 4; ct++) {
            bf16x8 wfrag = *(const bf16x8*)&wf[((ct * 8 + ks) * 64 + l) * 8];
            acc[ct] = __builtin_amdgcn_mfma_f32_32x32x16_bf16(wfrag, af[ks], acc[ct], 0, 0, 0);
        }
    }

    // ---- h1 = relu(D1 + b1): pack own 64 features as bf16 pairs ----
    unsigned P[4][4][2], Q[4][4][2];
#pragma unroll
    for (int ct = 0; ct < 4; ct++) {
#pragma unroll
        for (int g = 0; g < 4; g++) {
            float4 bv = *(const float4*)&cv[32 * ct + 8 * g + 4 * hi];
            float h0  = fmaxf(acc[ct][4 * g + 0] + bv.x, 0.f);
            float h1v = fmaxf(acc[ct][4 * g + 1] + bv.y, 0.f);
            float h2v = fmaxf(acc[ct][4 * g + 2] + bv.z, 0.f);
            float h3v = fmaxf(acc[ct][4 * g + 3] + bv.w, 0.f);
            P[ct][g][0] = pack2(h0, h1v);
            P[ct][g][1] = pack2(h2v, h3v);
        }
    }
#pragma unroll
    for (int ct = 0; ct < 4; ct++)
#pragma unroll
        for (int g = 0; g < 4; g++)
#pragma unroll
            for (int p = 0; p < 2; p++)
                Q[ct][g][p] = (unsigned)__shfl_xor((int)P[ct][g][p], 32, 64);

    __syncthreads();   // all waves done reading wf(W1)

    // ---- W2 transform into the same buffer ----
#pragma unroll
    for (int t = 0; t < 8; t++) {
        int rem = t * 256 + tid;
        int lv = rem & 63, ks = (rem >> 6) & 7, ct = rem >> 9;
        int k0 = ks * 16 + 8 * (lv >> 5);
        int n  = ct * 32 + (lv & 31);
        bf16x8 wv;
#pragma unroll
        for (int j = 0; j < 8; j++) wv[j] = f2bf(W2[(k0 + j) * HDIM + n]);
        *(bf16x8*)&wf[rem * 8] = wv;
    }
    __syncthreads();   // wf(W2) ready

    // ---- layer 2: B2 frag in-register; A = W2-frag from LDS ----
    f32x16 acc2[4];
#pragma unroll
    for (int ct = 0; ct < 4; ct++) acc2[ct] = zz;
#pragma unroll
    for (int ks2 = 0; ks2 < 8; ks2++) {
        const int c  = ks2 >> 1;
        const int s2 = (ks2 & 1) * 2;
        union { bf16x8 v; unsigned u[4]; } bb;
        bb.u[0] = hi ? Q[c][s2 + 1][0] : P[c][s2][0];
        bb.u[1] = hi ? Q[c][s2 + 1][1] : P[c][s2][1];
        bb.u[2] = hi ? P[c][s2 + 1][0] : Q[c][s2][0];
        bb.u[3] = hi ? P[c][s2 + 1][1] : Q[c][s2][1];
#pragma unroll
        for (int ct = 0; ct < 4; ct++) {
            bf16x8 wfrag = *(const bf16x8*)&wf[((ct * 8 + ks2) * 64 + l) * 8];
            acc2[ct] = __builtin_amdgcn_mfma_f32_32x32x16_bf16(wfrag, bb.v, acc2[ct], 0, 0, 0);
        }
    }

    // ---- epilogue: partial dot over own 64 n2, combine across lane pair ----
    float pq = 0.f, pk = 0.f;
#pragma unroll
    for (int ct = 0; ct < 4; ct++) {
#pragma unroll
        for (int g = 0; g < 4; g++) {
            float4 b2v = *(const float4*)&cv[128 + 32 * ct + 8 * g + 4 * hi];
            float4 wqv = *(const float4*)&cv[256 + 32 * ct + 8 * g + 4 * hi];
            float4 wkv = *(const float4*)&cv[384 + 32 * ct + 8 * g + 4 * hi];
            const float* b2a = (const float*)&b2v;
            const float* wqa = (const float*)&wqv;
            const float* wka = (const float*)&wkv;
#pragma unroll
            for (int i = 0; i < 4; i++) {
                float hv = fmaxf(acc2[ct][4 * g + i] + b2a[i], 0.f);
                pq = fmaf(hv, wqa[i], pq);
                pk = fmaf(hv, wka[i], pk);
            }
        }
    }
    pq += __shfl_xor(pq, 32, 64);
    pk += __shfl_xor(pk, 32, 64);
    if (hi == 0 && node < N) tab[node] = pack2(pq, pk);
}

// ---------------------------------------------------------------------------
// K2: edge pass (R8 verbatim — best measured): phase A = staging DMA + cast
// outputs + carry ein indices; phase B = gathers + score stores.
// ---------------------------------------------------------------------------
__global__ __launch_bounds__(1024) void edge_kernel(
    const int* __restrict__ eip, const int* __restrict__ ein,
    const unsigned* __restrict__ tab, const float* __restrict__ be_p,
    float* __restrict__ out, int E)
{
    __shared__ __align__(16) unsigned lt[LIM];   // 163840 B
    const int tid = threadIdx.x;
    const int wv = tid >> 6, ln = tid & 63;

    // ---- issue async staging DMA: 10240 uint4, 16 waves x 10 iters ----
    const uint4* tg4 = (const uint4*)tab;
#pragma unroll
    for (int t = 0; t < LIM / 4 / 1024; t++) {
        int c = (t * 16 + wv) * 64;
        __builtin_amdgcn_global_load_lds(
            (const __attribute__((address_space(1))) void*)(tg4 + c + ln),
            (__attribute__((address_space(3))) void*)((char*)lt + (size_t)c * 16),
            16, 0, 0);
    }
    __builtin_amdgcn_sched_barrier(0);

    const int U = E >> 2;                         // 4-edge units (E % 4 == 0)
    const int chunk = (U + gridDim.x - 1) / gridDim.x;
    const int ustart = blockIdx.x * chunk;
    const int uend = min(U, ustart + chunk);

    const int4* eip4 = (const int4*)eip;
    const int4* ein4 = (const int4*)ein;
    float4* out4 = (float4*)out;

    // ---- phase A: cast outputs (overlaps DMA); keep ein indices in regs ----
    const int u0 = ustart + tid, u1 = u0 + 1024;
    const bool v0 = u0 < uend, v1 = u1 < uend;
    int4 ns0 = {0,0,0,0}, nd0 = {0,0,0,0}, ns1 = {0,0,0,0}, nd1 = {0,0,0,0};
    if (v0) {
        ns0 = ein4[u0]; nd0 = ein4[U + u0];
        out4[2 * U + u0] = make_float4((float)ns0.x, (float)ns0.y, (float)ns0.z, (float)ns0.w);
        out4[3 * U + u0] = make_float4((float)nd0.x, (float)nd0.y, (float)nd0.z, (float)nd0.w);
    }
    if (v1) {
        ns1 = ein4[u1]; nd1 = ein4[U + u1];
        out4[2 * U + u1] = make_float4((float)ns1.x, (float)ns1.y, (float)ns1.z, (float)ns1.w);
        out4[3 * U + u1] = make_float4((float)nd1.x, (float)nd1.y, (float)nd1.z, (float)nd1.w);
    }
    __syncthreads();   // drains DMA (vmcnt) + makes lt visible

    const float be = be_p[0];
#define GATHER(i) ((i) < LIM ? lt[i] : tab[i])
#define SCORE(us, ud) (__uint_as_float((us) << 16) + __uint_as_float((ud) & 0xFFFF0000u) + be)

    // ---- phase B: score outputs ----
    if (v0) {
        int4 ps = eip4[u0], pd = eip4[U + u0];
        unsigned a0 = GATHER(ps.x), a1 = GATHER(ps.y), a2 = GATHER(ps.z), a3 = GATHER(ps.w);
        unsigned b0 = GATHER(pd.x), b1 = GATHER(pd.y), b2 = GATHER(pd.z), b3 = GATHER(pd.w);
        unsigned c0 = GATHER(ns0.x), c1 = GATHER(ns0.y), c2 = GATHER(ns0.z), c3 = GATHER(ns0.w);
        unsigned d0 = GATHER(nd0.x), d1 = GATHER(nd0.y), d2 = GATHER(nd0.z), d3 = GATHER(nd0.w);
        out4[u0]     = make_float4(SCORE(a0,b0), SCORE(a1,b1), SCORE(a2,b2), SCORE(a3,b3));
        out4[U + u0] = make_float4(SCORE(c0,d0), SCORE(c1,d1), SCORE(c2,d2), SCORE(c3,d3));
    }
    if (v1) {
        int4 ps = eip4[u1], pd = eip4[U + u1];
        unsigned a0 = GATHER(ps.x), a1 = GATHER(ps.y), a2 = GATHER(ps.z), a3 = GATHER(ps.w);
        unsigned b0 = GATHER(pd.x), b1 = GATHER(pd.y), b2 = GATHER(pd.z), b3 = GATHER(pd.w);
        unsigned c0 = GATHER(ns1.x), c1 = GATHER(ns1.y), c2 = GATHER(ns1.z), c3 = GATHER(ns1.w);
        unsigned d0 = GATHER(nd1.x), d1 = GATHER(nd1.y), d2 = GATHER(nd1.z), d3 = GATHER(nd1.w);
        out4[u1]     = make_float4(SCORE(a0,b0), SCORE(a1,b1), SCORE(a2,b2), SCORE(a3,b3));
        out4[U + u1] = make_float4(SCORE(c0,d0), SCORE(c1,d1), SCORE(c2,d2), SCORE(c3,d3));
    }
#undef GATHER
#undef SCORE
}

extern "C" void kernel_launch(void* const* d_in, const int* in_sizes, int n_in,
                              void* d_out, int out_size, void* d_ws, size_t ws_size,
                              hipStream_t stream) {
    const float* x   = (const float*)d_in[0];
    const int*   eip = (const int*)d_in[1];
    const int*   ein = (const int*)d_in[2];
    // d_in[3] = batch (unused)
    const float* W1  = (const float*)d_in[4];
    const float* b1  = (const float*)d_in[5];
    const float* W2  = (const float*)d_in[6];
    const float* b2  = (const float*)d_in[7];
    const float* We  = (const float*)d_in[8];
    const float* be  = (const float*)d_in[9];

    const int N = in_sizes[0] / CDIM;
    const int E = in_sizes[1] / 2;

    unsigned* tab = (unsigned*)d_ws;   // N*4 B packed bf16x2 score table

    node_mfma<<<(N + 127) / 128, 256, 0, stream>>>(x, W1, b1, W2, b2, We, tab, N);
    edge_kernel<<<256, 1024, 0, stream>>>(eip, ein, tab, be, (float*)d_out, E);
}

// Round 16
// 29.138 us; speedup vs baseline: 1.2947x; 1.2947x over previous
//
#include <hip/hip_runtime.h>

#define CDIM 128
#define HDIM 128
#define LIM  40960   // nodes cached in edge LDS (x4 B = 163840 B = full 160 KiB)

typedef short bf16x8 __attribute__((ext_vector_type(8)));
typedef float f32x16 __attribute__((ext_vector_type(16)));

// fp32 -> bf16 bits, round-to-nearest-even
static __device__ __forceinline__ short f2bf(float f) {
    union { float f; unsigned u; } v; v.f = f;
    unsigned r = v.u + 0x7FFFu + ((v.u >> 16) & 1u);
    return (short)(r >> 16);
}
static __device__ __forceinline__ unsigned pack2(float a, float b) {
    return (unsigned)(unsigned short)f2bf(a) | ((unsigned)(unsigned short)f2bf(b) << 16);
}

// ---------------------------------------------------------------------------
// K1: node MLP -> bf16x2 score table. One-layer LDS (34.8 KB) -> LDS-limited
// 4 blocks/CU (16 waves/CU). NO launch-bounds occupancy arg: compiler keeps
// ~88 VGPR (R15's (256,4) clamped to 64 -> spills -> 138 us; lesson learned).
// ---------------------------------------------------------------------------
__global__ __launch_bounds__(256) void node_mfma(
    const float* __restrict__ x,
    const float* __restrict__ W1, const float* __restrict__ b1,
    const float* __restrict__ W2, const float* __restrict__ b2,
    const float* __restrict__ We,
    unsigned* __restrict__ tab, int N)
{
    __shared__ __align__(16) short wf[16384];   // 32 KB: ONE layer
    __shared__ __align__(16) float cv[512];     // b1 | b2 | Wq | Wk

    const int tid = threadIdx.x;
    const int l   = tid & 63;
    const int col = l & 31;
    const int hi  = l >> 5;
    const int node = blockIdx.x * 128 + (tid >> 6) * 32 + col;

    // ---- issue ALL x loads first (latency hides under W1 transform) ----
    const int nclamp = (node < N) ? node : (N - 1);
    const float* xb = &x[(size_t)nclamp * CDIM + hi * 8];
    float4 xr[16];
#pragma unroll
    for (int ks = 0; ks < 8; ks++) {
        xr[2 * ks]     = *(const float4*)(xb + ks * 16);
        xr[2 * ks + 1] = *(const float4*)(xb + ks * 16 + 4);
    }

    // ---- W1 transform: dest-linear, 1 ds_write_b128/iter ----
#pragma unroll
    for (int t = 0; t < 8; t++) {
        int rem = t * 256 + tid;                 // 0..2047
        int lv = rem & 63, ks = (rem >> 6) & 7, ct = rem >> 9;
        int k0 = ks * 16 + 8 * (lv >> 5);
        int n  = ct * 32 + (lv & 31);
        bf16x8 wv;
#pragma unroll
        for (int j = 0; j < 8; j++) wv[j] = f2bf(W1[(k0 + j) * HDIM + n]);
        *(bf16x8*)&wf[rem * 8] = wv;
    }
    for (int i = tid; i < 512; i += 256)
        cv[i] = (i < 128) ? b1[i] : (i < 256) ? b2[i - 128] : We[i - 256];

    // ---- convert x to bf16 fragments ----
    bf16x8 af[8];
#pragma unroll
    for (int ks = 0; ks < 8; ks++) {
        float4 v0 = xr[2 * ks], v1 = xr[2 * ks + 1];
        af[ks][0] = f2bf(v0.x); af[ks][1] = f2bf(v0.y);
        af[ks][2] = f2bf(v0.z); af[ks][3] = f2bf(v0.w);
        af[ks][4] = f2bf(v1.x); af[ks][5] = f2bf(v1.y);
        af[ks][6] = f2bf(v1.z); af[ks][7] = f2bf(v1.w);
    }
    __syncthreads();   // wf(W1) + cv ready

    const f32x16 zz = {0.f,0.f,0.f,0.f,0.f,0.f,0.f,0.f,0.f,0.f,0.f,0.f,0.f,0.f,0.f,0.f};

    // ---- layer 1: A = W1-frag (LDS, lane-linear), B = x^T-frag (regs) ----
    f32x16 acc[4];
#pragma unroll
    for (int ct = 0; ct < 4; ct++) acc[ct] = zz;
#pragma unroll
    for (int ks = 0; ks < 8; ks++) {
#pragma unroll
        for (int ct = 0; ct < 4; ct++) {
            bf16x8 wfrag = *(const bf16x8*)&wf[((ct * 8 + ks) * 64 + l) * 8];
            acc[ct] = __builtin_amdgcn_mfma_f32_32x32x16_bf16(wfrag, af[ks], acc[ct], 0, 0, 0);
        }
    }

    // ---- h1 = relu(D1 + b1): pack own 64 features as bf16 pairs ----
    unsigned P[4][4][2], Q[4][4][2];
#pragma unroll
    for (int ct = 0; ct < 4; ct++) {
#pragma unroll
        for (int g = 0; g < 4; g++) {
            float4 bv = *(const float4*)&cv[32 * ct + 8 * g + 4 * hi];
            float h0  = fmaxf(acc[ct][4 * g + 0] + bv.x, 0.f);
            float h1v = fmaxf(acc[ct][4 * g + 1] + bv.y, 0.f);
            float h2v = fmaxf(acc[ct][4 * g + 2] + bv.z, 0.f);
            float h3v = fmaxf(acc[ct][4 * g + 3] + bv.w, 0.f);
            P[ct][g][0] = pack2(h0, h1v);
            P[ct][g][1] = pack2(h2v, h3v);
        }
    }
#pragma unroll
    for (int ct = 0; ct < 4; ct++)
#pragma unroll
        for (int g = 0; g < 4; g++)
#pragma unroll
            for (int p = 0; p < 2; p++)
                Q[ct][g][p] = (unsigned)__shfl_xor((int)P[ct][g][p], 32, 64);

    __syncthreads();   // all waves done reading wf(W1)

    // ---- W2 transform into the same buffer ----
#pragma unroll
    for (int t = 0; t < 8; t++) {
        int rem = t * 256 + tid;
        int lv = rem & 63, ks = (rem >> 6) & 7, ct = rem >> 9;
        int k0 = ks * 16 + 8 * (lv >> 5);
        int n  = ct * 32 + (lv & 31);
        bf16x8 wv;
#pragma unroll
        for (int j = 0; j < 8; j++) wv[j] = f2bf(W2[(k0 + j) * HDIM + n]);
        *(bf16x8*)&wf[rem * 8] = wv;
    }
    __syncthreads();   // wf(W2) ready

    // ---- layer 2: B2 frag in-register; A = W2-frag from LDS ----
    f32x16 acc2[4];
#pragma unroll
    for (int ct = 0; ct < 4; ct++) acc2[ct] = zz;
#pragma unroll
    for (int ks2 = 0; ks2 < 8; ks2++) {
        const int c  = ks2 >> 1;
        const int s2 = (ks2 & 1) * 2;
        union { bf16x8 v; unsigned u[4]; } bb;
        bb.u[0] = hi ? Q[c][s2 + 1][0] : P[c][s2][0];
        bb.u[1] = hi ? Q[c][s2 + 1][1] : P[c][s2][1];
        bb.u[2] = hi ? P[c][s2 + 1][0] : Q[c][s2][0];
        bb.u[3] = hi ? P[c][s2 + 1][1] : Q[c][s2][1];
#pragma unroll
        for (int ct = 0; ct < 4; ct++) {
            bf16x8 wfrag = *(const bf16x8*)&wf[((ct * 8 + ks2) * 64 + l) * 8];
            acc2[ct] = __builtin_amdgcn_mfma_f32_32x32x16_bf16(wfrag, bb.v, acc2[ct], 0, 0, 0);
        }
    }

    // ---- epilogue: partial dot over own 64 n2, combine across lane pair ----
    float pq = 0.f, pk = 0.f;
#pragma unroll
    for (int ct = 0; ct < 4; ct++) {
#pragma unroll
        for (int g = 0; g < 4; g++) {
            float4 b2v = *(const float4*)&cv[128 + 32 * ct + 8 * g + 4 * hi];
            float4 wqv = *(const float4*)&cv[256 + 32 * ct + 8 * g + 4 * hi];
            float4 wkv = *(const float4*)&cv[384 + 32 * ct + 8 * g + 4 * hi];
            const float* b2a = (const float*)&b2v;
            const float* wqa = (const float*)&wqv;
            const float* wka = (const float*)&wkv;
#pragma unroll
            for (int i = 0; i < 4; i++) {
                float hv = fmaxf(acc2[ct][4 * g + i] + b2a[i], 0.f);
                pq = fmaf(hv, wqa[i], pq);
                pk = fmaf(hv, wka[i], pk);
            }
        }
    }
    pq += __shfl_xor(pq, 32, 64);
    pk += __shfl_xor(pk, 32, 64);
    if (hi == 0 && node < N) tab[node] = pack2(pq, pk);
}

// ---------------------------------------------------------------------------
// K2: edge pass (R8 verbatim — best measured): phase A = staging DMA + cast
// outputs + carry ein indices; phase B = gathers + score stores.
// ---------------------------------------------------------------------------
__global__ __launch_bounds__(1024) void edge_kernel(
    const int* __restrict__ eip, const int* __restrict__ ein,
    const unsigned* __restrict__ tab, const float* __restrict__ be_p,
    float* __restrict__ out, int E)
{
    __shared__ __align__(16) unsigned lt[LIM];   // 163840 B
    const int tid = threadIdx.x;
    const int wv = tid >> 6, ln = tid & 63;

    // ---- issue async staging DMA: 10240 uint4, 16 waves x 10 iters ----
    const uint4* tg4 = (const uint4*)tab;
#pragma unroll
    for (int t = 0; t < LIM / 4 / 1024; t++) {
        int c = (t * 16 + wv) * 64;
        __builtin_amdgcn_global_load_lds(
            (const __attribute__((address_space(1))) void*)(tg4 + c + ln),
            (__attribute__((address_space(3))) void*)((char*)lt + (size_t)c * 16),
            16, 0, 0);
    }
    __builtin_amdgcn_sched_barrier(0);

    const int U = E >> 2;                         // 4-edge units (E % 4 == 0)
    const int chunk = (U + gridDim.x - 1) / gridDim.x;
    const int ustart = blockIdx.x * chunk;
    const int uend = min(U, ustart + chunk);

    const int4* eip4 = (const int4*)eip;
    const int4* ein4 = (const int4*)ein;
    float4* out4 = (float4*)out;

    // ---- phase A: cast outputs (overlaps DMA); keep ein indices in regs ----
    const int u0 = ustart + tid, u1 = u0 + 1024;
    const bool v0 = u0 < uend, v1 = u1 < uend;
    int4 ns0 = {0,0,0,0}, nd0 = {0,0,0,0}, ns1 = {0,0,0,0}, nd1 = {0,0,0,0};
    if (v0) {
        ns0 = ein4[u0]; nd0 = ein4[U + u0];
        out4[2 * U + u0] = make_float4((float)ns0.x, (float)ns0.y, (float)ns0.z, (float)ns0.w);
        out4[3 * U + u0] = make_float4((float)nd0.x, (float)nd0.y, (float)nd0.z, (float)nd0.w);
    }
    if (v1) {
        ns1 = ein4[u1]; nd1 = ein4[U + u1];
        out4[2 * U + u1] = make_float4((float)ns1.x, (float)ns1.y, (float)ns1.z, (float)ns1.w);
        out4[3 * U + u1] = make_float4((float)nd1.x, (float)nd1.y, (float)nd1.z, (float)nd1.w);
    }
    __syncthreads();   // drains DMA (vmcnt) + makes lt visible

    const float be = be_p[0];
#define GATHER(i) ((i) < LIM ? lt[i] : tab[i])
#define SCORE(us, ud) (__uint_as_float((us) << 16) + __uint_as_float((ud) & 0xFFFF0000u) + be)

    // ---- phase B: score outputs ----
    if (v0) {
        int4 ps = eip4[u0], pd = eip4[U + u0];
        unsigned a0 = GATHER(ps.x), a1 = GATHER(ps.y), a2 = GATHER(ps.z), a3 = GATHER(ps.w);
        unsigned b0 = GATHER(pd.x), b1 = GATHER(pd.y), b2 = GATHER(pd.z), b3 = GATHER(pd.w);
        unsigned c0 = GATHER(ns0.x), c1 = GATHER(ns0.y), c2 = GATHER(ns0.z), c3 = GATHER(ns0.w);
        unsigned d0 = GATHER(nd0.x), d1 = GATHER(nd0.y), d2 = GATHER(nd0.z), d3 = GATHER(nd0.w);
        out4[u0]     = make_float4(SCORE(a0,b0), SCORE(a1,b1), SCORE(a2,b2), SCORE(a3,b3));
        out4[U + u0] = make_float4(SCORE(c0,d0), SCORE(c1,d1), SCORE(c2,d2), SCORE(c3,d3));
    }
    if (v1) {
        int4 ps = eip4[u1], pd = eip4[U + u1];
        unsigned a0 = GATHER(ps.x), a1 = GATHER(ps.y), a2 = GATHER(ps.z), a3 = GATHER(ps.w);
        unsigned b0 = GATHER(pd.x), b1 = GATHER(pd.y), b2 = GATHER(pd.z), b3 = GATHER(pd.w);
        unsigned c0 = GATHER(ns1.x), c1 = GATHER(ns1.y), c2 = GATHER(ns1.z), c3 = GATHER(ns1.w);
        unsigned d0 = GATHER(nd1.x), d1 = GATHER(nd1.y), d2 = GATHER(nd1.z), d3 = GATHER(nd1.w);
        out4[u1]     = make_float4(SCORE(a0,b0), SCORE(a1,b1), SCORE(a2,b2), SCORE(a3,b3));
        out4[U + u1] = make_float4(SCORE(c0,d0), SCORE(c1,d1), SCORE(c2,d2), SCORE(c3,d3));
    }
#undef GATHER
#undef SCORE
}

extern "C" void kernel_launch(void* const* d_in, const int* in_sizes, int n_in,
                              void* d_out, int out_size, void* d_ws, size_t ws_size,
                              hipStream_t stream) {
    const float* x   = (const float*)d_in[0];
    const int*   eip = (const int*)d_in[1];
    const int*   ein = (const int*)d_in[2];
    // d_in[3] = batch (unused)
    const float* W1  = (const float*)d_in[4];
    const float* b1  = (const float*)d_in[5];
    const float* W2  = (const float*)d_in[6];
    const float* b2  = (const float*)d_in[7];
    const float* We  = (const float*)d_in[8];
    const float* be  = (const float*)d_in[9];

    const int N = in_sizes[0] / CDIM;
    const int E = in_sizes[1] / 2;

    unsigned* tab = (unsigned*)d_ws;   // N*4 B packed bf16x2 score table

    node_mfma<<<(N + 127) / 128, 256, 0, stream>>>(x, W1, b1, W2, b2, We, tab, N);
    edge_kernel<<<256, 1024, 0, stream>>>(eip, ein, tab, be, (float*)d_out, E);
}

// Round 17
// 28.748 us; speedup vs baseline: 1.3122x; 1.0136x over previous
//
#include <hip/hip_runtime.h>

#define CDIM 128
#define HDIM 128
#define LIM  40960   // nodes cached in edge LDS (x4 B = 163840 B = full 160 KiB)

typedef short bf16x8 __attribute__((ext_vector_type(8)));
typedef float f32x16 __attribute__((ext_vector_type(16)));

// fp32 -> bf16 bits, round-to-nearest-even
static __device__ __forceinline__ short f2bf(float f) {
    union { float f; unsigned u; } v; v.f = f;
    unsigned r = v.u + 0x7FFFu + ((v.u >> 16) & 1u);
    return (short)(r >> 16);
}
static __device__ __forceinline__ unsigned pack2(float a, float b) {
    return (unsigned)(unsigned short)f2bf(a) | ((unsigned)(unsigned short)f2bf(b) << 16);
}

// ---------------------------------------------------------------------------
// K1: node MLP -> bf16x2 score table. 256 nodes/block (512 thr, 8 waves),
// ONE-layer LDS (34.8 KB), W2 restaged mid-kernel. Halves the W-transform
// count vs 128-node blocks (196 vs 391). VGPR ~88 -> 2 blocks/CU = 16
// waves/CU (same TLP as R16). No launch-bounds occupancy clamp (R15 lesson).
// ---------------------------------------------------------------------------
__global__ __launch_bounds__(512) void node_mfma(
    const float* __restrict__ x,
    const float* __restrict__ W1, const float* __restrict__ b1,
    const float* __restrict__ W2, const float* __restrict__ b2,
    const float* __restrict__ We,
    unsigned* __restrict__ tab, int N)
{
    __shared__ __align__(16) short wf[16384];   // 32 KB: ONE layer
    __shared__ __align__(16) float cv[512];     // b1 | b2 | Wq | Wk

    const int tid = threadIdx.x;
    const int l   = tid & 63;
    const int col = l & 31;
    const int hi  = l >> 5;
    const int node = blockIdx.x * 256 + (tid >> 6) * 32 + col;

    // ---- issue ALL x loads first (latency hides under W1 transform) ----
    const int nclamp = (node < N) ? node : (N - 1);
    const float* xb = &x[(size_t)nclamp * CDIM + hi * 8];
    float4 xr[16];
#pragma unroll
    for (int ks = 0; ks < 8; ks++) {
        xr[2 * ks]     = *(const float4*)(xb + ks * 16);
        xr[2 * ks + 1] = *(const float4*)(xb + ks * 16 + 4);
    }

    // ---- W1 transform: dest-linear, 1 ds_write_b128/iter, 4 iters/thread ----
#pragma unroll
    for (int t = 0; t < 4; t++) {
        int rem = t * 512 + tid;                 // 0..2047
        int lv = rem & 63, ks = (rem >> 6) & 7, ct = rem >> 9;
        int k0 = ks * 16 + 8 * (lv >> 5);
        int n  = ct * 32 + (lv & 31);
        bf16x8 wv;
#pragma unroll
        for (int j = 0; j < 8; j++) wv[j] = f2bf(W1[(k0 + j) * HDIM + n]);
        *(bf16x8*)&wf[rem * 8] = wv;
    }
    if (tid < 512)
        cv[tid] = (tid < 128) ? b1[tid] : (tid < 256) ? b2[tid - 128] : We[tid - 256];

    // ---- convert x to bf16 fragments ----
    bf16x8 af[8];
#pragma unroll
    for (int ks = 0; ks < 8; ks++) {
        float4 v0 = xr[2 * ks], v1 = xr[2 * ks + 1];
        af[ks][0] = f2bf(v0.x); af[ks][1] = f2bf(v0.y);
        af[ks][2] = f2bf(v0.z); af[ks][3] = f2bf(v0.w);
        af[ks][4] = f2bf(v1.x); af[ks][5] = f2bf(v1.y);
        af[ks][6] = f2bf(v1.z); af[ks][7] = f2bf(v1.w);
    }
    __syncthreads();   // wf(W1) + cv ready

    const f32x16 zz = {0.f,0.f,0.f,0.f,0.f,0.f,0.f,0.f,0.f,0.f,0.f,0.f,0.f,0.f,0.f,0.f};

    // ---- layer 1: A = W1-frag (LDS, lane-linear), B = x^T-frag (regs) ----
    f32x16 acc[4];
#pragma unroll
    for (int ct = 0; ct < 4; ct++) acc[ct] = zz;
#pragma unroll
    for (int ks = 0; ks < 8; ks++) {
#pragma unroll
        for (int ct = 0; ct < 4; ct++) {
            bf16x8 wfrag = *(const bf16x8*)&wf[((ct * 8 + ks) * 64 + l) * 8];
            acc[ct] = __builtin_amdgcn_mfma_f32_32x32x16_bf16(wfrag, af[ks], acc[ct], 0, 0, 0);
        }
    }

    // ---- h1 = relu(D1 + b1): pack own 64 features as bf16 pairs ----
    unsigned P[4][4][2], Q[4][4][2];
#pragma unroll
    for (int ct = 0; ct < 4; ct++) {
#pragma unroll
        for (int g = 0; g < 4; g++) {
            float4 bv = *(const float4*)&cv[32 * ct + 8 * g + 4 * hi];
            float h0  = fmaxf(acc[ct][4 * g + 0] + bv.x, 0.f);
            float h1v = fmaxf(acc[ct][4 * g + 1] + bv.y, 0.f);
            float h2v = fmaxf(acc[ct][4 * g + 2] + bv.z, 0.f);
            float h3v = fmaxf(acc[ct][4 * g + 3] + bv.w, 0.f);
            P[ct][g][0] = pack2(h0, h1v);
            P[ct][g][1] = pack2(h2v, h3v);
        }
    }
#pragma unroll
    for (int ct = 0; ct < 4; ct++)
#pragma unroll
        for (int g = 0; g < 4; g++)
#pragma unroll
            for (int p = 0; p < 2; p++)
                Q[ct][g][p] = (unsigned)__shfl_xor((int)P[ct][g][p], 32, 64);

    __syncthreads();   // all waves done reading wf(W1)

    // ---- W2 transform into the same buffer ----
#pragma unroll
    for (int t = 0; t < 4; t++) {
        int rem = t * 512 + tid;
        int lv = rem & 63, ks = (rem >> 6) & 7, ct = rem >> 9;
        int k0 = ks * 16 + 8 * (lv >> 5);
        int n  = ct * 32 + (lv & 31);
        bf16x8 wv;
#pragma unroll
        for (int j = 0; j < 8; j++) wv[j] = f2bf(W2[(k0 + j) * HDIM + n]);
        *(bf16x8*)&wf[rem * 8] = wv;
    }
    __syncthreads();   // wf(W2) ready

    // ---- layer 2: B2 frag in-register; A = W2-frag from LDS ----
    f32x16 acc2[4];
#pragma unroll
    for (int ct = 0; ct < 4; ct++) acc2[ct] = zz;
#pragma unroll
    for (int ks2 = 0; ks2 < 8; ks2++) {
        const int c  = ks2 >> 1;
        const int s2 = (ks2 & 1) * 2;
        union { bf16x8 v; unsigned u[4]; } bb;
        bb.u[0] = hi ? Q[c][s2 + 1][0] : P[c][s2][0];
        bb.u[1] = hi ? Q[c][s2 + 1][1] : P[c][s2][1];
        bb.u[2] = hi ? P[c][s2 + 1][0] : Q[c][s2][0];
        bb.u[3] = hi ? P[c][s2 + 1][1] : Q[c][s2][1];
#pragma unroll
        for (int ct = 0; ct < 4; ct++) {
            bf16x8 wfrag = *(const bf16x8*)&wf[((ct * 8 + ks2) * 64 + l) * 8];
            acc2[ct] = __builtin_amdgcn_mfma_f32_32x32x16_bf16(wfrag, bb.v, acc2[ct], 0, 0, 0);
        }
    }

    // ---- epilogue: partial dot over own 64 n2, combine across lane pair ----
    float pq = 0.f, pk = 0.f;
#pragma unroll
    for (int ct = 0; ct < 4; ct++) {
#pragma unroll
        for (int g = 0; g < 4; g++) {
            float4 b2v = *(const float4*)&cv[128 + 32 * ct + 8 * g + 4 * hi];
            float4 wqv = *(const float4*)&cv[256 + 32 * ct + 8 * g + 4 * hi];
            float4 wkv = *(const float4*)&cv[384 + 32 * ct + 8 * g + 4 * hi];
            const float* b2a = (const float*)&b2v;
            const float* wqa = (const float*)&wqv;
            const float* wka = (const float*)&wkv;
#pragma unroll
            for (int i = 0; i < 4; i++) {
                float hv = fmaxf(acc2[ct][4 * g + i] + b2a[i], 0.f);
                pq = fmaf(hv, wqa[i], pq);
                pk = fmaf(hv, wka[i], pk);
            }
        }
    }
    pq += __shfl_xor(pq, 32, 64);
    pk += __shfl_xor(pk, 32, 64);
    if (hi == 0 && node < N) tab[node] = pack2(pq, pk);
}

// ---------------------------------------------------------------------------
// K2: edge pass (R8/R16 verbatim — best measured): phase A = staging DMA +
// cast outputs + carry ein indices; phase B = gathers + score stores.
// ---------------------------------------------------------------------------
__global__ __launch_bounds__(1024) void edge_kernel(
    const int* __restrict__ eip, const int* __restrict__ ein,
    const unsigned* __restrict__ tab, const float* __restrict__ be_p,
    float* __restrict__ out, int E)
{
    __shared__ __align__(16) unsigned lt[LIM];   // 163840 B
    const int tid = threadIdx.x;
    const int wv = tid >> 6, ln = tid & 63;

    // ---- issue async staging DMA: 10240 uint4, 16 waves x 10 iters ----
    const uint4* tg4 = (const uint4*)tab;
#pragma unroll
    for (int t = 0; t < LIM / 4 / 1024; t++) {
        int c = (t * 16 + wv) * 64;
        __builtin_amdgcn_global_load_lds(
            (const __attribute__((address_space(1))) void*)(tg4 + c + ln),
            (__attribute__((address_space(3))) void*)((char*)lt + (size_t)c * 16),
            16, 0, 0);
    }
    __builtin_amdgcn_sched_barrier(0);

    const int U = E >> 2;                         // 4-edge units (E % 4 == 0)
    const int chunk = (U + gridDim.x - 1) / gridDim.x;
    const int ustart = blockIdx.x * chunk;
    const int uend = min(U, ustart + chunk);

    const int4* eip4 = (const int4*)eip;
    const int4* ein4 = (const int4*)ein;
    float4* out4 = (float4*)out;

    // ---- phase A: cast outputs (overlaps DMA); keep ein indices in regs ----
    const int u0 = ustart + tid, u1 = u0 + 1024;
    const bool v0 = u0 < uend, v1 = u1 < uend;
    int4 ns0 = {0,0,0,0}, nd0 = {0,0,0,0}, ns1 = {0,0,0,0}, nd1 = {0,0,0,0};
    if (v0) {
        ns0 = ein4[u0]; nd0 = ein4[U + u0];
        out4[2 * U + u0] = make_float4((float)ns0.x, (float)ns0.y, (float)ns0.z, (float)ns0.w);
        out4[3 * U + u0] = make_float4((float)nd0.x, (float)nd0.y, (float)nd0.z, (float)nd0.w);
    }
    if (v1) {
        ns1 = ein4[u1]; nd1 = ein4[U + u1];
        out4[2 * U + u1] = make_float4((float)ns1.x, (float)ns1.y, (float)ns1.z, (float)ns1.w);
        out4[3 * U + u1] = make_float4((float)nd1.x, (float)nd1.y, (float)nd1.z, (float)nd1.w);
    }
    __syncthreads();   // drains DMA (vmcnt) + makes lt visible

    const float be = be_p[0];
#define GATHER(i) ((i) < LIM ? lt[i] : tab[i])
#define SCORE(us, ud) (__uint_as_float((us) << 16) + __uint_as_float((ud) & 0xFFFF0000u) + be)

    // ---- phase B: score outputs ----
    if (v0) {
        int4 ps = eip4[u0], pd = eip4[U + u0];
        unsigned a0 = GATHER(ps.x), a1 = GATHER(ps.y), a2 = GATHER(ps.z), a3 = GATHER(ps.w);
        unsigned b0 = GATHER(pd.x), b1 = GATHER(pd.y), b2 = GATHER(pd.z), b3 = GATHER(pd.w);
        unsigned c0 = GATHER(ns0.x), c1 = GATHER(ns0.y), c2 = GATHER(ns0.z), c3 = GATHER(ns0.w);
        unsigned d0 = GATHER(nd0.x), d1 = GATHER(nd0.y), d2 = GATHER(nd0.z), d3 = GATHER(nd0.w);
        out4[u0]     = make_float4(SCORE(a0,b0), SCORE(a1,b1), SCORE(a2,b2), SCORE(a3,b3));
        out4[U + u0] = make_float4(SCORE(c0,d0), SCORE(c1,d1), SCORE(c2,d2), SCORE(c3,d3));
    }
    if (v1) {
        int4 ps = eip4[u1], pd = eip4[U + u1];
        unsigned a0 = GATHER(ps.x), a1 = GATHER(ps.y), a2 = GATHER(ps.z), a3 = GATHER(ps.w);
        unsigned b0 = GATHER(pd.x), b1 = GATHER(pd.y), b2 = GATHER(pd.z), b3 = GATHER(pd.w);
        unsigned c0 = GATHER(ns1.x), c1 = GATHER(ns1.y), c2 = GATHER(ns1.z), c3 = GATHER(ns1.w);
        unsigned d0 = GATHER(nd1.x), d1 = GATHER(nd1.y), d2 = GATHER(nd1.z), d3 = GATHER(nd1.w);
        out4[u1]     = make_float4(SCORE(a0,b0), SCORE(a1,b1), SCORE(a2,b2), SCORE(a3,b3));
        out4[U + u1] = make_float4(SCORE(c0,d0), SCORE(c1,d1), SCORE(c2,d2), SCORE(c3,d3));
    }
#undef GATHER
#undef SCORE
}

extern "C" void kernel_launch(void* const* d_in, const int* in_sizes, int n_in,
                              void* d_out, int out_size, void* d_ws, size_t ws_size,
                              hipStream_t stream) {
    const float* x   = (const float*)d_in[0];
    const int*   eip = (const int*)d_in[1];
    const int*   ein = (const int*)d_in[2];
    // d_in[3] = batch (unused)
    const float* W1  = (const float*)d_in[4];
    const float* b1  = (const float*)d_in[5];
    const float* W2  = (const float*)d_in[6];
    const float* b2  = (const float*)d_in[7];
    const float* We  = (const float*)d_in[8];
    const float* be  = (const float*)d_in[9];

    const int N = in_sizes[0] / CDIM;
    const int E = in_sizes[1] / 2;

    unsigned* tab = (unsigned*)d_ws;   // N*4 B packed bf16x2 score table

    node_mfma<<<(N + 255) / 256, 512, 0, stream>>>(x, W1, b1, W2, b2, We, tab, N);
    edge_kernel<<<256, 1024, 0, stream>>>(eip, ein, tab, be, (float*)d_out, E);
}

// Round 18
// 28.636 us; speedup vs baseline: 1.3174x; 1.0039x over previous
//
#include <hip/hip_runtime.h>

#define CDIM 128
#define HDIM 128
#define LIM  40960   // nodes cached in edge LDS (x4 B = 163840 B = full 160 KiB)

typedef short bf16x8 __attribute__((ext_vector_type(8)));
typedef float f32x16 __attribute__((ext_vector_type(16)));

// fp32 -> bf16 bits, round-to-nearest-even
static __device__ __forceinline__ short f2bf(float f) {
    union { float f; unsigned u; } v; v.f = f;
    unsigned r = v.u + 0x7FFFu + ((v.u >> 16) & 1u);
    return (short)(r >> 16);
}
static __device__ __forceinline__ unsigned pack2(float a, float b) {
    return (unsigned)(unsigned short)f2bf(a) | ((unsigned)(unsigned short)f2bf(b) << 16);
}

// ---------------------------------------------------------------------------
// K1: node MLP -> bf16x2 score table (R17 verbatim — best measured).
// 256 nodes/block (512 thr), one-layer LDS, W2 restage mid-kernel.
// ---------------------------------------------------------------------------
__global__ __launch_bounds__(512) void node_mfma(
    const float* __restrict__ x,
    const float* __restrict__ W1, const float* __restrict__ b1,
    const float* __restrict__ W2, const float* __restrict__ b2,
    const float* __restrict__ We,
    unsigned* __restrict__ tab, int N)
{
    __shared__ __align__(16) short wf[16384];   // 32 KB: ONE layer
    __shared__ __align__(16) float cv[512];     // b1 | b2 | Wq | Wk

    const int tid = threadIdx.x;
    const int l   = tid & 63;
    const int col = l & 31;
    const int hi  = l >> 5;
    const int node = blockIdx.x * 256 + (tid >> 6) * 32 + col;

    // ---- issue ALL x loads first (latency hides under W1 transform) ----
    const int nclamp = (node < N) ? node : (N - 1);
    const float* xb = &x[(size_t)nclamp * CDIM + hi * 8];
    float4 xr[16];
#pragma unroll
    for (int ks = 0; ks < 8; ks++) {
        xr[2 * ks]     = *(const float4*)(xb + ks * 16);
        xr[2 * ks + 1] = *(const float4*)(xb + ks * 16 + 4);
    }

    // ---- W1 transform: dest-linear, 1 ds_write_b128/iter, 4 iters/thread ----
#pragma unroll
    for (int t = 0; t < 4; t++) {
        int rem = t * 512 + tid;                 // 0..2047
        int lv = rem & 63, ks = (rem >> 6) & 7, ct = rem >> 9;
        int k0 = ks * 16 + 8 * (lv >> 5);
        int n  = ct * 32 + (lv & 31);
        bf16x8 wv;
#pragma unroll
        for (int j = 0; j < 8; j++) wv[j] = f2bf(W1[(k0 + j) * HDIM + n]);
        *(bf16x8*)&wf[rem * 8] = wv;
    }
    if (tid < 512)
        cv[tid] = (tid < 128) ? b1[tid] : (tid < 256) ? b2[tid - 128] : We[tid - 256];

    // ---- convert x to bf16 fragments ----
    bf16x8 af[8];
#pragma unroll
    for (int ks = 0; ks < 8; ks++) {
        float4 v0 = xr[2 * ks], v1 = xr[2 * ks + 1];
        af[ks][0] = f2bf(v0.x); af[ks][1] = f2bf(v0.y);
        af[ks][2] = f2bf(v0.z); af[ks][3] = f2bf(v0.w);
        af[ks][4] = f2bf(v1.x); af[ks][5] = f2bf(v1.y);
        af[ks][6] = f2bf(v1.z); af[ks][7] = f2bf(v1.w);
    }
    __syncthreads();   // wf(W1) + cv ready

    const f32x16 zz = {0.f,0.f,0.f,0.f,0.f,0.f,0.f,0.f,0.f,0.f,0.f,0.f,0.f,0.f,0.f,0.f};

    // ---- layer 1: A = W1-frag (LDS, lane-linear), B = x^T-frag (regs) ----
    f32x16 acc[4];
#pragma unroll
    for (int ct = 0; ct < 4; ct++) acc[ct] = zz;
#pragma unroll
    for (int ks = 0; ks < 8; ks++) {
#pragma unroll
        for (int ct = 0; ct < 4; ct++) {
            bf16x8 wfrag = *(const bf16x8*)&wf[((ct * 8 + ks) * 64 + l) * 8];
            acc[ct] = __builtin_amdgcn_mfma_f32_32x32x16_bf16(wfrag, af[ks], acc[ct], 0, 0, 0);
        }
    }

    // ---- h1 = relu(D1 + b1): pack own 64 features as bf16 pairs ----
    unsigned P[4][4][2], Q[4][4][2];
#pragma unroll
    for (int ct = 0; ct < 4; ct++) {
#pragma unroll
        for (int g = 0; g < 4; g++) {
            float4 bv = *(const float4*)&cv[32 * ct + 8 * g + 4 * hi];
            float h0  = fmaxf(acc[ct][4 * g + 0] + bv.x, 0.f);
            float h1v = fmaxf(acc[ct][4 * g + 1] + bv.y, 0.f);
            float h2v = fmaxf(acc[ct][4 * g + 2] + bv.z, 0.f);
            float h3v = fmaxf(acc[ct][4 * g + 3] + bv.w, 0.f);
            P[ct][g][0] = pack2(h0, h1v);
            P[ct][g][1] = pack2(h2v, h3v);
        }
    }
#pragma unroll
    for (int ct = 0; ct < 4; ct++)
#pragma unroll
        for (int g = 0; g < 4; g++)
#pragma unroll
            for (int p = 0; p < 2; p++)
                Q[ct][g][p] = (unsigned)__shfl_xor((int)P[ct][g][p], 32, 64);

    __syncthreads();   // all waves done reading wf(W1)

    // ---- W2 transform into the same buffer ----
#pragma unroll
    for (int t = 0; t < 4; t++) {
        int rem = t * 512 + tid;
        int lv = rem & 63, ks = (rem >> 6) & 7, ct = rem >> 9;
        int k0 = ks * 16 + 8 * (lv >> 5);
        int n  = ct * 32 + (lv & 31);
        bf16x8 wv;
#pragma unroll
        for (int j = 0; j < 8; j++) wv[j] = f2bf(W2[(k0 + j) * HDIM + n]);
        *(bf16x8*)&wf[rem * 8] = wv;
    }
    __syncthreads();   // wf(W2) ready

    // ---- layer 2: B2 frag in-register; A = W2-frag from LDS ----
    f32x16 acc2[4];
#pragma unroll
    for (int ct = 0; ct < 4; ct++) acc2[ct] = zz;
#pragma unroll
    for (int ks2 = 0; ks2 < 8; ks2++) {
        const int c  = ks2 >> 1;
        const int s2 = (ks2 & 1) * 2;
        union { bf16x8 v; unsigned u[4]; } bb;
        bb.u[0] = hi ? Q[c][s2 + 1][0] : P[c][s2][0];
        bb.u[1] = hi ? Q[c][s2 + 1][1] : P[c][s2][1];
        bb.u[2] = hi ? P[c][s2 + 1][0] : Q[c][s2][0];
        bb.u[3] = hi ? P[c][s2 + 1][1] : Q[c][s2][1];
#pragma unroll
        for (int ct = 0; ct < 4; ct++) {
            bf16x8 wfrag = *(const bf16x8*)&wf[((ct * 8 + ks2) * 64 + l) * 8];
            acc2[ct] = __builtin_amdgcn_mfma_f32_32x32x16_bf16(wfrag, bb.v, acc2[ct], 0, 0, 0);
        }
    }

    // ---- epilogue: partial dot over own 64 n2, combine across lane pair ----
    float pq = 0.f, pk = 0.f;
#pragma unroll
    for (int ct = 0; ct < 4; ct++) {
#pragma unroll
        for (int g = 0; g < 4; g++) {
            float4 b2v = *(const float4*)&cv[128 + 32 * ct + 8 * g + 4 * hi];
            float4 wqv = *(const float4*)&cv[256 + 32 * ct + 8 * g + 4 * hi];
            float4 wkv = *(const float4*)&cv[384 + 32 * ct + 8 * g + 4 * hi];
            const float* b2a = (const float*)&b2v;
            const float* wqa = (const float*)&wqv;
            const float* wka = (const float*)&wkv;
#pragma unroll
            for (int i = 0; i < 4; i++) {
                float hv = fmaxf(acc2[ct][4 * g + i] + b2a[i], 0.f);
                pq = fmaf(hv, wqa[i], pq);
                pk = fmaf(hv, wka[i], pk);
            }
        }
    }
    pq += __shfl_xor(pq, 32, 64);
    pk += __shfl_xor(pk, 32, 64);
    if (hi == 0 && node < N) tab[node] = pack2(pq, pk);
}

// ---------------------------------------------------------------------------
// K2: edge pass with FIFO-vmcnt-aware issue order: index preloads are issued
// BEFORE the staging DMA (vmcnt is FIFO — consuming a load issued after the
// DMA would drain the whole DMA first; issuing indices first means they
// complete at vmcnt(10) while the DMA is still in flight). Casts are computed
// and stored mid-DMA. Phase B carries ein + eip(u0); eip(u1) loads at phase-B
// start, hidden under u0's gather+store work.
// ---------------------------------------------------------------------------
__global__ __launch_bounds__(1024) void edge_kernel(
    const int* __restrict__ eip, const int* __restrict__ ein,
    const unsigned* __restrict__ tab, const float* __restrict__ be_p,
    float* __restrict__ out, int E)
{
    __shared__ __align__(16) unsigned lt[LIM];   // 163840 B
    const int tid = threadIdx.x;
    const int wv = tid >> 6, ln = tid & 63;

    const int U = E >> 2;                         // 4-edge units (E % 4 == 0)
    const int chunk = (U + gridDim.x - 1) / gridDim.x;
    const int ustart = blockIdx.x * chunk;
    const int uend = min(U, ustart + chunk);

    const int4* eip4 = (const int4*)eip;
    const int4* ein4 = (const int4*)ein;
    float4* out4 = (float4*)out;

    const int u0 = ustart + tid, u1 = u0 + 1024;
    const bool v0 = u0 < uend, v1 = u1 < uend;

    // ---- step 1: issue index preloads (OLDEST in the vmcnt FIFO) ----
    int4 ns0 = {0,0,0,0}, nd0 = {0,0,0,0}, ns1 = {0,0,0,0}, nd1 = {0,0,0,0};
    int4 ps0 = {0,0,0,0}, pd0 = {0,0,0,0};
    if (v0) { ns0 = ein4[u0]; nd0 = ein4[U + u0]; ps0 = eip4[u0]; pd0 = eip4[U + u0]; }
    if (v1) { ns1 = ein4[u1]; nd1 = ein4[U + u1]; }
    __builtin_amdgcn_sched_barrier(0);   // pin: index loads issue before DMA

    // ---- step 2: issue staging DMA: 10240 uint4, 16 waves x 10 iters ----
    const uint4* tg4 = (const uint4*)tab;
#pragma unroll
    for (int t = 0; t < LIM / 4 / 1024; t++) {
        int c = (t * 16 + wv) * 64;
        __builtin_amdgcn_global_load_lds(
            (const __attribute__((address_space(1))) void*)(tg4 + c + ln),
            (__attribute__((address_space(3))) void*)((char*)lt + (size_t)c * 16),
            16, 0, 0);
    }
    __builtin_amdgcn_sched_barrier(0);   // pin: DMA issued before cast waits

    // ---- step 3: cast outputs — indices complete at vmcnt(10), mid-DMA ----
    if (v0) {
        out4[2 * U + u0] = make_float4((float)ns0.x, (float)ns0.y, (float)ns0.z, (float)ns0.w);
        out4[3 * U + u0] = make_float4((float)nd0.x, (float)nd0.y, (float)nd0.z, (float)nd0.w);
    }
    if (v1) {
        out4[2 * U + u1] = make_float4((float)ns1.x, (float)ns1.y, (float)ns1.z, (float)ns1.w);
        out4[3 * U + u1] = make_float4((float)nd1.x, (float)nd1.y, (float)nd1.z, (float)nd1.w);
    }
    __syncthreads();   // drains DMA (vmcnt 0) + makes lt visible

    const float be = be_p[0];
#define GATHER(i) ((i) < LIM ? lt[i] : tab[i])
#define SCORE(us, ud) (__uint_as_float((us) << 16) + __uint_as_float((ud) & 0xFFFF0000u) + be)

    // ---- phase B: u1's eip loads issue first, hidden under u0's work ----
    int4 ps1 = {0,0,0,0}, pd1 = {0,0,0,0};
    if (v1) { ps1 = eip4[u1]; pd1 = eip4[U + u1]; }

    if (v0) {
        unsigned a0 = GATHER(ps0.x), a1 = GATHER(ps0.y), a2 = GATHER(ps0.z), a3 = GATHER(ps0.w);
        unsigned b0 = GATHER(pd0.x), b1 = GATHER(pd0.y), b2 = GATHER(pd0.z), b3 = GATHER(pd0.w);
        out4[u0] = make_float4(SCORE(a0,b0), SCORE(a1,b1), SCORE(a2,b2), SCORE(a3,b3));
        unsigned c0 = GATHER(ns0.x), c1 = GATHER(ns0.y), c2 = GATHER(ns0.z), c3 = GATHER(ns0.w);
        unsigned d0 = GATHER(nd0.x), d1 = GATHER(nd0.y), d2 = GATHER(nd0.z), d3 = GATHER(nd0.w);
        out4[U + u0] = make_float4(SCORE(c0,d0), SCORE(c1,d1), SCORE(c2,d2), SCORE(c3,d3));
    }
    if (v1) {
        unsigned a0 = GATHER(ps1.x), a1 = GATHER(ps1.y), a2 = GATHER(ps1.z), a3 = GATHER(ps1.w);
        unsigned b0 = GATHER(pd1.x), b1 = GATHER(pd1.y), b2 = GATHER(pd1.z), b3 = GATHER(pd1.w);
        out4[u1] = make_float4(SCORE(a0,b0), SCORE(a1,b1), SCORE(a2,b2), SCORE(a3,b3));
        unsigned c0 = GATHER(ns1.x), c1 = GATHER(ns1.y), c2 = GATHER(ns1.z), c3 = GATHER(ns1.w);
        unsigned d0 = GATHER(nd1.x), d1 = GATHER(nd1.y), d2 = GATHER(nd1.z), d3 = GATHER(nd1.w);
        out4[U + u1] = make_float4(SCORE(c0,d0), SCORE(c1,d1), SCORE(c2,d2), SCORE(c3,d3));
    }
#undef GATHER
#undef SCORE
}

extern "C" void kernel_launch(void* const* d_in, const int* in_sizes, int n_in,
                              void* d_out, int out_size, void* d_ws, size_t ws_size,
                              hipStream_t stream) {
    const float* x   = (const float*)d_in[0];
    const int*   eip = (const int*)d_in[1];
    const int*   ein = (const int*)d_in[2];
    // d_in[3] = batch (unused)
    const float* W1  = (const float*)d_in[4];
    const float* b1  = (const float*)d_in[5];
    const float* W2  = (const float*)d_in[6];
    const float* b2  = (const float*)d_in[7];
    const float* We  = (const float*)d_in[8];
    const float* be  = (const float*)d_in[9];

    const int N = in_sizes[0] / CDIM;
    const int E = in_sizes[1] / 2;

    unsigned* tab = (unsigned*)d_ws;   // N*4 B packed bf16x2 score table

    node_mfma<<<(N + 255) / 256, 512, 0, stream>>>(x, W1, b1, W2, b2, We, tab, N);
    edge_kernel<<<256, 1024, 0, stream>>>(eip, ein, tab, be, (float*)d_out, E);
}